// Round 1
// baseline (1308.020 us; speedup 1.0000x reference)
//
#include <hip/hip_runtime.h>

#define H    32
#define SEQ  1440
#define NT   (SEQ - 1)   // 1439 steps produce output; step 1439 is dead code
#define INP  11
#define TC   64          // timesteps per chunk (x staging + deferred FC)

__device__ __forceinline__ float rcp_fast(float x) { return __builtin_amdgcn_rcpf(x); }
__device__ __forceinline__ float tanh_f(float x) {
    // tanh(x) = 2*sigmoid(2x) - 1 ; v_exp/v_rcp ~1-2 ULP, contractive dynamics keep drift tiny
    return fmaf(2.f, rcp_fast(1.f + __expf(-2.f * x)), -1.f);
}

// Block = 128 threads (2 waves) = one batch sample.
// Thread (wave wv, lane l): gate-type q = l>>4 (0:i 1:f 2:g 3:o), hidden idx jj = wv*16 + (l&15).
// Weight row r = q*32 + jj. All weight rows live in registers for the whole kernel.
__global__ __launch_bounds__(128, 2)
void lstm_fused_kernel(const float* __restrict__ x,
                       const float* __restrict__ Wih0, const float* __restrict__ Whh0,
                       const float* __restrict__ bih0, const float* __restrict__ bhh0,
                       const float* __restrict__ Wih1, const float* __restrict__ Whh1,
                       const float* __restrict__ bih1, const float* __restrict__ bhh1,
                       const float* __restrict__ fc1w_g, const float* __restrict__ fc1b_g,
                       const float* __restrict__ fc2w_g, const float* __restrict__ fc2b_g,
                       float* __restrict__ out)
{
    __shared__ float h0s[2][H];      // double-buffered layer-0 h
    __shared__ float h1s[2][H];      // double-buffered layer-1 h
    __shared__ float xs[TC][12];     // x chunk, [t][i] padded 11->12 (16B aligned rows)
    __shared__ float h1c[TC][36];    // layer-1 h history for deferred FC (36: bank-conflict pad)

    const int tid  = threadIdx.x;
    const int lane = tid & 63;
    const int wv   = tid >> 6;
    const int m    = lane & 15;
    const int q    = lane >> 4;
    const int jj   = wv * 16 + m;
    const int r    = q * 32 + jj;
    const int b    = blockIdx.x;

    // ---- load weights into registers (one-time; L2/L3 cached across blocks) ----
    float wih0[12];
    #pragma unroll
    for (int i = 0; i < INP; ++i) wih0[i] = Wih0[r * INP + i];
    wih0[11] = 0.f;                      // pad so x row can be consumed as 3x float4
    float whh0[H], wih1[H], whh1[H];
    #pragma unroll
    for (int k = 0; k < H; ++k) {
        whh0[k] = Whh0[r * H + k];
        wih1[k] = Wih1[r * H + k];
        whh1[k] = Whh1[r * H + k];
    }
    const float bs0 = bih0[r] + bhh0[r];
    const float bs1 = bih1[r] + bhh1[r];
    const int   u   = tid & 15;          // FC unit owned by this thread
    float fcw[H];
    #pragma unroll
    for (int k = 0; k < H; ++k) fcw[k] = fc1w_g[u * H + k];
    const float fcb = fc1b_g[u];
    const float f2w = fc2w_g[u];
    const float f2b = fc2b_g[0];

    if (tid < H) { h0s[0][tid] = 0.f; h1s[0][tid] = 0.f; }
    float c0 = 0.f, c1 = 0.f;

    const float* xb   = x   + (size_t)b * INP * SEQ;   // x[b][i][t], t contiguous
    float*       outb = out + (size_t)b * NT;

    __syncthreads();

    for (int cbase = 0; cbase < NT; cbase += TC) {
        const int clen = min(TC, NT - cbase);

        // ---- stage x[b][:, cbase:cbase+clen] into LDS (coalesced over t) ----
        {
            const int col = tid & 63;
            const int r2  = tid >> 6;
            #pragma unroll
            for (int ib = 0; ib < 12; ib += 2) {
                const int row = ib + r2;
                if (row < INP && col < clen)
                    xs[col][row] = xb[row * SEQ + cbase + col];
            }
        }
        __syncthreads();

        for (int tc = 0; tc < clen; ++tc) {
            const int p = (cbase + tc) & 1;   // h double-buffer parity

            // ================= layer 0 =================
            float act;
            {
                const float4* xv = (const float4*)xs[tc];
                const float4* hv = (const float4*)h0s[p];
                float ax = bs0, a0 = 0.f, a1 = 0.f;
                float4 x0 = xv[0], x1 = xv[1], x2 = xv[2];
                ax = fmaf(wih0[0],  x0.x, ax); ax = fmaf(wih0[1],  x0.y, ax);
                ax = fmaf(wih0[2],  x0.z, ax); ax = fmaf(wih0[3],  x0.w, ax);
                ax = fmaf(wih0[4],  x1.x, ax); ax = fmaf(wih0[5],  x1.y, ax);
                ax = fmaf(wih0[6],  x1.z, ax); ax = fmaf(wih0[7],  x1.w, ax);
                ax = fmaf(wih0[8],  x2.x, ax); ax = fmaf(wih0[9],  x2.y, ax);
                ax = fmaf(wih0[10], x2.z, ax);
                #pragma unroll
                for (int kk = 0; kk < 4; ++kk) {
                    float4 ha = hv[kk], hb = hv[kk + 4];
                    a0 = fmaf(whh0[4*kk+0],    ha.x, a0);
                    a0 = fmaf(whh0[4*kk+1],    ha.y, a0);
                    a0 = fmaf(whh0[4*kk+2],    ha.z, a0);
                    a0 = fmaf(whh0[4*kk+3],    ha.w, a0);
                    a1 = fmaf(whh0[16+4*kk+0], hb.x, a1);
                    a1 = fmaf(whh0[16+4*kk+1], hb.y, a1);
                    a1 = fmaf(whh0[16+4*kk+2], hb.z, a1);
                    a1 = fmaf(whh0[16+4*kk+3], hb.w, a1);
                }
                float a  = (ax + a0) + a1;
                float sc = (q == 2) ? 2.f : 1.f;           // branchless: tanh = 2*sigm(2a)-1
                float s  = rcp_fast(1.f + __expf(-sc * a));
                act = (q == 2) ? fmaf(2.f, s, -1.f) : s;
            }
            // gates i,f,g,o live at lanes l, l+16, l+32, l+48 of this wave
            float gf = __shfl_xor(act, 16);
            float gg = __shfl_xor(act, 32);
            float go = __shfl_xor(act, 48);
            if (q == 0) {
                c0 = fmaf(gf, c0, act * gg);
                h0s[p ^ 1][jj] = go * tanh_f(c0);
            }
            __syncthreads();   // h0 new visible to both waves

            // ================= layer 1 =================
            {
                const float4* hav = (const float4*)h0s[p ^ 1];  // layer-1 input = new h0
                const float4* hbv = (const float4*)h1s[p];      // recurrent = old h1
                float a0 = bs1, a1 = 0.f, a2 = 0.f, a3 = 0.f;
                #pragma unroll
                for (int kk = 0; kk < 4; ++kk) {
                    float4 ha = hav[kk], ha2 = hav[kk + 4];
                    float4 hb = hbv[kk], hb2 = hbv[kk + 4];
                    a0 = fmaf(wih1[4*kk+0],    ha.x,  a0); a0 = fmaf(wih1[4*kk+1],    ha.y,  a0);
                    a0 = fmaf(wih1[4*kk+2],    ha.z,  a0); a0 = fmaf(wih1[4*kk+3],    ha.w,  a0);
                    a1 = fmaf(wih1[16+4*kk+0], ha2.x, a1); a1 = fmaf(wih1[16+4*kk+1], ha2.y, a1);
                    a1 = fmaf(wih1[16+4*kk+2], ha2.z, a1); a1 = fmaf(wih1[16+4*kk+3], ha2.w, a1);
                    a2 = fmaf(whh1[4*kk+0],    hb.x,  a2); a2 = fmaf(whh1[4*kk+1],    hb.y,  a2);
                    a2 = fmaf(whh1[4*kk+2],    hb.z,  a2); a2 = fmaf(whh1[4*kk+3],    hb.w,  a2);
                    a3 = fmaf(whh1[16+4*kk+0], hb2.x, a3); a3 = fmaf(whh1[16+4*kk+1], hb2.y, a3);
                    a3 = fmaf(whh1[16+4*kk+2], hb2.z, a3); a3 = fmaf(whh1[16+4*kk+3], hb2.w, a3);
                }
                float a  = (a0 + a1) + (a2 + a3);
                float sc = (q == 2) ? 2.f : 1.f;
                float s  = rcp_fast(1.f + __expf(-sc * a));
                act = (q == 2) ? fmaf(2.f, s, -1.f) : s;
            }
            gf = __shfl_xor(act, 16);
            gg = __shfl_xor(act, 32);
            go = __shfl_xor(act, 48);
            if (q == 0) {
                c1 = fmaf(gf, c1, act * gg);
                float hn = go * tanh_f(c1);
                h1s[p ^ 1][jj] = hn;
                h1c[tc][jj]    = hn;   // history for deferred FC
            }
            __syncthreads();   // h1 new + h1c visible
        }

        // ---- deferred FC head over the chunk: 16 units x clen steps, all 128 threads ----
        #pragma unroll
        for (int rep = 0; rep < 8; ++rep) {
            const int tcl = (tid >> 4) + 8 * rep;   // uniform within each 16-lane group
            if (tcl < clen) {
                const float4* hv = (const float4*)h1c[tcl];
                float a0 = fcb, a1 = 0.f;
                #pragma unroll
                for (int kk = 0; kk < 4; ++kk) {
                    float4 ha = hv[kk], hb = hv[kk + 4];
                    a0 = fmaf(fcw[4*kk+0],    ha.x, a0); a0 = fmaf(fcw[4*kk+1],    ha.y, a0);
                    a0 = fmaf(fcw[4*kk+2],    ha.z, a0); a0 = fmaf(fcw[4*kk+3],    ha.w, a0);
                    a1 = fmaf(fcw[16+4*kk+0], hb.x, a1); a1 = fmaf(fcw[16+4*kk+1], hb.y, a1);
                    a1 = fmaf(fcw[16+4*kk+2], hb.z, a1); a1 = fmaf(fcw[16+4*kk+3], hb.w, a1);
                }
                float yv = tanh_f(a0 + a1) * f2w;
                yv += __shfl_xor(yv, 1);
                yv += __shfl_xor(yv, 2);
                yv += __shfl_xor(yv, 4);
                yv += __shfl_xor(yv, 8);
                if (u == 0) outb[cbase + tcl] = yv + f2b;
            }
        }
        __syncthreads();
    }
}

extern "C" void kernel_launch(void* const* d_in, const int* in_sizes, int n_in,
                              void* d_out, int out_size, void* d_ws, size_t ws_size,
                              hipStream_t stream)
{
    const float* x    = (const float*)d_in[0];
    const float* Wih0 = (const float*)d_in[1];
    const float* Whh0 = (const float*)d_in[2];
    const float* bih0 = (const float*)d_in[3];
    const float* bhh0 = (const float*)d_in[4];
    const float* Wih1 = (const float*)d_in[5];
    const float* Whh1 = (const float*)d_in[6];
    const float* bih1 = (const float*)d_in[7];
    const float* bhh1 = (const float*)d_in[8];
    const float* fc1w = (const float*)d_in[9];
    const float* fc1b = (const float*)d_in[10];
    const float* fc2w = (const float*)d_in[11];
    const float* fc2b = (const float*)d_in[12];
    float* out = (float*)d_out;

    const int B = in_sizes[0] / (INP * SEQ);   // 1024
    dim3 grid(B), block(128);
    hipLaunchKernelGGL(lstm_fused_kernel, grid, block, 0, stream,
                       x, Wih0, Whh0, bih0, bhh0, Wih1, Whh1, bih1, bhh1,
                       fc1w, fc1b, fc2w, fc2b, out);
}